// Round 1
// baseline (572.879 us; speedup 1.0000x reference)
//
#include <hip/hip_runtime.h>
#include <cstdint>
#include <cstddef>

#define NBm 256
#define NAm 96
#define NDm 384
#define NHm 192
#define NFm 96
#define NSm 4
#define NATOMS (NBm*NAm)      /* 24576 */
#define NEe (NATOMS*32)       /* 786432 */
#define CUTOFF_ 5.2f

typedef __attribute__((ext_vector_type(8))) short short8;
typedef __attribute__((ext_vector_type(4))) float float4v;

__device__ __forceinline__ short f2bf(float f){
  union { float f; unsigned u; } v; v.f = f;
  unsigned r = v.u + 0x7FFFu + ((v.u >> 16) & 1u);
  return (short)(r >> 16);
}

// jax.nn.gelu default: tanh approximation
__device__ __forceinline__ float gelu_t(float x){
  float u = 0.7978845608028654f * (x + 0.044715f * x*x*x);
  float e = __expf(-2.0f * fabsf(u));
  float t = (1.0f - e) / (1.0f + e);
  t = (u >= 0.f) ? t : -t;
  return 0.5f * x * (1.0f + t);
}

__global__ void k_zero(int* __restrict__ cnt, int* __restrict__ spc){
  int i = blockIdx.x*256 + threadIdx.x;
  if (i < NATOMS) cnt[i] = 0;
  if (i < NSm) spc[i] = 0;
}

// per-endpoint degree count + per-edge decay weight
__global__ void k_edge(const int* __restrict__ ai, const float* __restrict__ dist,
                       const float* __restrict__ pref, const float* __restrict__ fac,
                       int* __restrict__ cnt, float* __restrict__ decay){
  int e = blockIdx.x*256 + threadIdx.x;
  if (e < 2*NEe) atomicAdd(&cnt[ai[e]], 1);
  if (e < NEe){
    float d = dist[e];
    float x = (CUTOFF_ - d) * (1.0f/CUTOFF_);
    x = fminf(fmaxf(x, 0.f), 1.f);
    float sc = x*x*x*(x*(6.f*x - 15.f) + 10.f);
    float p = pref[0], fc = fac[0];
    decay[e] = p*p * expf(-fc*fc*d) * sc;
  }
}

// exclusive scan over cnt[NATOMS]; 1024 threads x 24 elems each (24576 exact)
__global__ void k_scan(const int* __restrict__ cnt, int* __restrict__ rs, int* __restrict__ cur){
  __shared__ int sums[1024];
  int t = threadIdx.x;
  int base = t * 24;
  int tot = 0;
  int loc[24];
  #pragma unroll
  for (int j=0;j<24;j++){ loc[j] = cnt[base+j]; tot += loc[j]; }
  sums[t] = tot; __syncthreads();
  for (int off=1; off<1024; off<<=1){
    int v = (t >= off) ? sums[t-off] : 0;
    __syncthreads();
    sums[t] += v;
    __syncthreads();
  }
  int run = sums[t] - tot;
  #pragma unroll
  for (int j=0;j<24;j++){
    rs[base+j] = run; cur[base+j] = run;
    run += loc[j];
  }
  if (t == 1023) rs[NATOMS] = run;
}

__global__ void k_spcount(const int* __restrict__ sp, int* __restrict__ spc){
  __shared__ int h[NSm];
  int t = threadIdx.x;
  if (t < NSm) h[t] = 0;
  __syncthreads();
  int i = blockIdx.x*256 + t;     // grid = 96 exact
  atomicAdd(&h[sp[i]], 1);
  __syncthreads();
  if (t < NSm) atomicAdd(&spc[t], h[t]);
}

__global__ void k_spscan(const int* __restrict__ spc, int* __restrict__ sps, int* __restrict__ spcur){
  if (threadIdx.x==0 && blockIdx.x==0){
    int r=0;
    for (int s=0;s<NSm;s++){ sps[s]=r; spcur[s]=r; r+=spc[s]; }
    sps[NSm]=r;
  }
}

__global__ void k_spscatter(const int* __restrict__ sp, int* __restrict__ spcur,
                            int* __restrict__ order){
  __shared__ int h[NSm], base[NSm];
  int t = threadIdx.x;
  if (t < NSm) h[t]=0;
  __syncthreads();
  int i = blockIdx.x*256 + t;
  int s = sp[i];
  int lr = atomicAdd(&h[s], 1);
  __syncthreads();
  if (t < NSm) base[t] = atomicAdd(&spcur[t], h[t]);
  __syncthreads();
  order[base[s] + lr] = i;
}

__global__ void k_fill(const int* __restrict__ ai, const float* __restrict__ decay,
                       int* __restrict__ cur, int* __restrict__ co, float* __restrict__ cw){
  int e = blockIdx.x*256 + threadIdx.x;
  if (e >= 2*NEe) return;
  int dst = ai[e];
  int o   = (e < NEe) ? ai[e+NEe] : ai[e-NEe];
  float w = decay[(e < NEe) ? e : e - NEe];
  int pos = atomicAdd(&cur[dst], 1);
  co[pos] = o; cw[pos] = w;
}

// Fused per-species MLP: internal = gelu(X@W1)@W2 ; nbr = internal@Wn
// 64 rows/block, 4 waves, mfma_f32_16x16x32_bf16
// A layout: A[m=lane&15][k=quad*8+j]; B supplied transposed: B[n=lane&15][k=quad*8+j]
// C/D layout: col=lane&15, row=quad*4+reg
__global__ __launch_bounds__(256) void k_mlp(
    const float* __restrict__ X, const int* __restrict__ order,
    const int* __restrict__ sps,
    const float* __restrict__ W1, const float* __restrict__ W2, const float* __restrict__ Wn,
    float* __restrict__ internal_g, float* __restrict__ nbr_g){
  const int s = blockIdx.y;
  const int s0 = sps[s];
  const int cnt = sps[s+1] - s0;
  const int row0 = blockIdx.x * 64;
  if (row0 >= cnt) return;

  __shared__ short Hs[64][200];     // H tile bf16, padded
  __shared__ short Ws[192*40];      // transposed weight chunk [col][k<=32], padded to 40
  __shared__ short Is[64][104];     // internal tile bf16, padded
  __shared__ int aids[64];

  const int tid = threadIdx.x;
  if (tid < 64){
    int r = row0 + tid;
    aids[tid] = order[s0 + ((r < cnt) ? r : 0)];
  }
  __syncthreads();

  const int wave = tid >> 6, lane = tid & 63;
  const int lrow = lane & 15, quad = lane >> 4;
  const int arow = wave*16 + lrow;
  const float* xrow = X + (size_t)aids[arow]*NDm + quad*8;

  // preload & convert all A fragments (GEMM1) up front
  short8 afs[12];
  #pragma unroll
  for (int kb=0; kb<12; kb++){
    const float* p = xrow + kb*32;
    #pragma unroll
    for (int j=0;j<8;j++) afs[kb][j] = f2bf(p[j]);
  }

  const float* W1s = W1 + s*NDm*NHm;
  float4v acc[12];
  #pragma unroll
  for (int i=0;i<12;i++){ acc[i][0]=0.f; acc[i][1]=0.f; acc[i][2]=0.f; acc[i][3]=0.f; }

  // ---- GEMM1: [64,384]@[384,192]
  for (int kb=0; kb<12; kb++){
    __syncthreads();
    for (int e = tid; e < 32*192; e += 256){
      int k = e / 192, c = e - k*192;
      Ws[c*40 + k] = f2bf(W1s[(kb*32 + k)*NHm + c]);
    }
    __syncthreads();
    short8 af = afs[kb];
    #pragma unroll
    for (int ct=0; ct<12; ct++){
      short8 bfb = *(const short8*)(&Ws[(ct*16 + lrow)*40 + quad*8]);
      acc[ct] = __builtin_amdgcn_mfma_f32_16x16x32_bf16(af, bfb, acc[ct], 0,0,0);
    }
  }
  // gelu -> Hs (bf16)
  #pragma unroll
  for (int ct=0; ct<12; ct++){
    #pragma unroll
    for (int r=0;r<4;r++){
      Hs[wave*16 + quad*4 + r][ct*16 + lrow] = f2bf(gelu_t(acc[ct][r]));
    }
  }

  // ---- GEMM2: [64,192]@[192,96]
  const float* W2s = W2 + s*NHm*NFm;
  float4v acc2[6];
  #pragma unroll
  for (int i=0;i<6;i++){ acc2[i][0]=0.f; acc2[i][1]=0.f; acc2[i][2]=0.f; acc2[i][3]=0.f; }
  for (int kb=0; kb<6; kb++){
    __syncthreads();
    for (int e = tid; e < 32*96; e += 256){
      int k = e / 96, c = e - k*96;
      Ws[c*40 + k] = f2bf(W2s[(kb*32 + k)*NFm + c]);
    }
    __syncthreads();
    short8 af2 = *(const short8*)(&Hs[wave*16 + lrow][kb*32 + quad*8]);
    #pragma unroll
    for (int ct=0; ct<6; ct++){
      short8 bfb = *(const short8*)(&Ws[(ct*16 + lrow)*40 + quad*8]);
      acc2[ct] = __builtin_amdgcn_mfma_f32_16x16x32_bf16(af2, bfb, acc2[ct], 0,0,0);
    }
  }
  // store internal (f32) + Is (bf16)
  #pragma unroll
  for (int ct=0; ct<6; ct++){
    #pragma unroll
    for (int r=0;r<4;r++){
      int row = wave*16 + quad*4 + r, col = ct*16 + lrow;
      float v = acc2[ct][r];
      if (row0 + row < cnt) internal_g[(size_t)aids[row]*NFm + col] = v;
      Is[row][col] = f2bf(v);
    }
  }

  // ---- GEMM3: [64,96]@[96,96]
  const float* Wns = Wn + s*NFm*NFm;
  float4v acc3[6];
  #pragma unroll
  for (int i=0;i<6;i++){ acc3[i][0]=0.f; acc3[i][1]=0.f; acc3[i][2]=0.f; acc3[i][3]=0.f; }
  for (int kb=0; kb<3; kb++){
    __syncthreads();
    for (int e = tid; e < 32*96; e += 256){
      int k = e / 96, c = e - k*96;
      Ws[c*40 + k] = f2bf(Wns[(kb*32 + k)*NFm + c]);
    }
    __syncthreads();
    short8 af3 = *(const short8*)(&Is[wave*16 + lrow][kb*32 + quad*8]);
    #pragma unroll
    for (int ct=0; ct<6; ct++){
      short8 bfb = *(const short8*)(&Ws[(ct*16 + lrow)*40 + quad*8]);
      acc3[ct] = __builtin_amdgcn_mfma_f32_16x16x32_bf16(af3, bfb, acc3[ct], 0,0,0);
    }
  }
  #pragma unroll
  for (int ct=0; ct<6; ct++){
    #pragma unroll
    for (int r=0;r<4;r++){
      int row = wave*16 + quad*4 + r, col = ct*16 + lrow;
      if (row0 + row < cnt) nbr_g[(size_t)aids[row]*NFm + col] = acc3[ct][r];
    }
  }
}

// gather merged + head (precharges). 192 threads = 2 atoms x 96 features.
__global__ void k_merge_head(const int* __restrict__ rs, const int* __restrict__ co,
                             const float* __restrict__ cw, const float* __restrict__ nbr,
                             const float* __restrict__ internal, const int* __restrict__ sp,
                             const float* __restrict__ Wf, float* __restrict__ pre_out){
  __shared__ float red[2][128];
  int tid = threadIdx.x;
  int la = tid / 96, f = tid - la*96;
  int i = blockIdx.x*2 + la;
  int s = sp[i];
  int e0 = rs[i], e1 = rs[i+1];
  float acc = 0.f;
  for (int e = e0; e < e1; e++){
    acc += cw[e] * nbr[(size_t)co[e]*NFm + f];
  }
  float contrib = internal[(size_t)i*NFm + f] * Wf[s*192 + f] + acc * Wf[s*192 + 96 + f];
  red[la][f] = contrib;
  if (f < 32) red[la][96 + f] = 0.f;
  __syncthreads();
  for (int off=64; off>0; off>>=1){
    if (f < off) red[la][f] += red[la][f + off];
    __syncthreads();
  }
  if (f == 0) pre_out[i] = red[la][0];
}

// per-molecule charge redistribution + species passthrough
__global__ void k_finalize(const int* __restrict__ sp, const float* __restrict__ tc,
                           const float* __restrict__ pre, float* __restrict__ out){
  __shared__ float red[128];
  int b = blockIdx.x, t = threadIdx.x;
  float p = (t < NAm) ? pre[b*NAm + t] : 0.f;
  red[t] = p;
  __syncthreads();
  for (int off=64; off>0; off>>=1){
    if (t < off) red[t] += red[t + off];
    __syncthreads();
  }
  float sum = red[0];
  if (t < NAm){
    float c = p + (tc[b] - sum) * (1.0f/96.0f);
    out[b*NAm + t] = (float)sp[b*NAm + t];        // species as float
    out[NATOMS + b*NAm + t] = c;                  // charges
  }
}

extern "C" void kernel_launch(void* const* d_in, const int* in_sizes, int n_in,
                              void* d_out, int out_size, void* d_ws, size_t ws_size,
                              hipStream_t stream) {
  const int*   species = (const int*)  d_in[0];
  const float* X       = (const float*)d_in[1];
  const int*   ai      = (const int*)  d_in[2];
  const float* dist    = (const float*)d_in[3];
  const float* tc      = (const float*)d_in[4];
  const float* W1      = (const float*)d_in[5];
  const float* W2      = (const float*)d_in[6];
  const float* Wn      = (const float*)d_in[7];
  const float* Wf      = (const float*)d_in[8];
  const float* pref    = (const float*)d_in[9];
  const float* fac     = (const float*)d_in[10];
  float* out = (float*)d_out;

  char* w = (char*)d_ws;
  auto alloc = [&](size_t bytes)->char*{
    char* p = w; w += (bytes + 255) & ~(size_t)255; return p;
  };
  float* decay    = (float*)alloc((size_t)NEe*4);
  int*   cnt      = (int*)  alloc((size_t)NATOMS*4);
  int*   rs       = (int*)  alloc((size_t)(NATOMS+1)*4);
  int*   cur      = (int*)  alloc((size_t)NATOMS*4);
  int*   spc      = (int*)  alloc(64);
  int*   sps      = (int*)  alloc(64);
  int*   spcur    = (int*)  alloc(64);
  int*   order    = (int*)  alloc((size_t)NATOMS*4);
  int*   co       = (int*)  alloc((size_t)2*NEe*4);
  float* cw       = (float*)alloc((size_t)2*NEe*4);
  float* internal = (float*)alloc((size_t)NATOMS*NFm*4);
  float* nbr      = (float*)alloc((size_t)NATOMS*NFm*4);

  k_zero<<<(NATOMS+255)/256, 256, 0, stream>>>(cnt, spc);
  k_edge<<<(2*NEe+255)/256, 256, 0, stream>>>(ai, dist, pref, fac, cnt, decay);
  k_scan<<<1, 1024, 0, stream>>>(cnt, rs, cur);
  k_spcount<<<NATOMS/256, 256, 0, stream>>>(species, spc);
  k_spscan<<<1, 64, 0, stream>>>(spc, sps, spcur);
  k_spscatter<<<NATOMS/256, 256, 0, stream>>>(species, spcur, order);
  k_fill<<<(2*NEe+255)/256, 256, 0, stream>>>(ai, decay, cur, co, cw);
  dim3 g(NATOMS/64, NSm);
  k_mlp<<<g, 256, 0, stream>>>(X, order, sps, W1, W2, Wn, internal, nbr);
  k_merge_head<<<NATOMS/2, 192, 0, stream>>>(rs, co, cw, nbr, internal, species, Wf,
                                             out + 2*NATOMS);
  k_finalize<<<NBm, 128, 0, stream>>>(species, tc, out + 2*NATOMS, out);
}

// Round 3
// 277.783 us; speedup vs baseline: 2.0623x; 2.0623x over previous
//
#include <hip/hip_runtime.h>
#include <cstdint>
#include <cstddef>

#define NBm 256
#define NAm 96
#define NDm 384
#define NHm 192
#define NFm 96
#define NSm 4
#define NATOMS (NBm*NAm)      /* 24576 */
#define NEe (NATOMS*32)       /* 786432 */
#define CUTOFF_ 5.2f

typedef __attribute__((ext_vector_type(8))) short short8;
typedef __attribute__((ext_vector_type(4))) float float4v;

__device__ __forceinline__ short f2bf(float f){
  union { float f; unsigned u; } v; v.f = f;
  unsigned r = v.u + 0x7FFFu + ((v.u >> 16) & 1u);
  return (short)(r >> 16);
}

// jax.nn.gelu default: tanh approximation
__device__ __forceinline__ float gelu_t(float x){
  float u = 0.7978845608028654f * (x + 0.044715f * x*x*x);
  float e = __expf(-2.0f * fabsf(u));
  float t = (1.0f - e) / (1.0f + e);
  t = (u >= 0.f) ? t : -t;
  return 0.5f * x * (1.0f + t);
}

// ---------- species sort ----------
__global__ void k_zero4(int* __restrict__ spc){
  if (threadIdx.x < NSm) spc[threadIdx.x] = 0;
}

__global__ void k_spcount(const int* __restrict__ sp, int* __restrict__ spc){
  __shared__ int h[NSm];
  int t = threadIdx.x;
  if (t < NSm) h[t] = 0;
  __syncthreads();
  int i = blockIdx.x*256 + t;     // grid = 96 exact
  atomicAdd(&h[sp[i]], 1);
  __syncthreads();
  if (t < NSm) atomicAdd(&spc[t], h[t]);
}

__global__ void k_spscan(const int* __restrict__ spc, int* __restrict__ sps, int* __restrict__ spcur){
  if (threadIdx.x==0 && blockIdx.x==0){
    int r=0;
    for (int s=0;s<NSm;s++){ sps[s]=r; spcur[s]=r; r+=spc[s]; }
    sps[NSm]=r;
  }
}

__global__ void k_spscatter(const int* __restrict__ sp, int* __restrict__ spcur,
                            int* __restrict__ order){
  __shared__ int h[NSm], base[NSm];
  int t = threadIdx.x;
  if (t < NSm) h[t]=0;
  __syncthreads();
  int i = blockIdx.x*256 + t;
  int s = sp[i];
  int lr = atomicAdd(&h[s], 1);
  __syncthreads();
  if (t < NSm) base[t] = atomicAdd(&spcur[t], h[t]);
  __syncthreads();
  order[base[s] + lr] = i;
}

// ---------- fused per-species MLP (Round-1 verified body) ----------
// internal = gelu(X@W1)@W2 ; nbr = internal@Wn
// 64 rows/block, 4 waves, mfma_f32_16x16x32_bf16
// A layout: A[m=lane&15][k=quad*8+j]; B supplied transposed: B[n=lane&15][k=quad*8+j]
// C/D layout: col=lane&15, row=quad*4+reg
__global__ __launch_bounds__(256) void k_mlp(
    const float* __restrict__ X, const int* __restrict__ order,
    const int* __restrict__ sps,
    const float* __restrict__ W1, const float* __restrict__ W2, const float* __restrict__ Wn,
    float* __restrict__ internal_g, float* __restrict__ nbr_g){
  const int s = blockIdx.y;
  const int s0 = sps[s];
  const int cnt = sps[s+1] - s0;
  const int row0 = blockIdx.x * 64;
  if (row0 >= cnt) return;

  __shared__ short Hs[64][200];     // H tile bf16, padded
  __shared__ short Ws[192*40];      // transposed weight chunk [col][k<=32], padded to 40
  __shared__ short Is[64][104];     // internal tile bf16, padded
  __shared__ int aids[64];

  const int tid = threadIdx.x;
  if (tid < 64){
    int r = row0 + tid;
    aids[tid] = order[s0 + ((r < cnt) ? r : 0)];
  }
  __syncthreads();

  const int wave = tid >> 6, lane = tid & 63;
  const int lrow = lane & 15, quad = lane >> 4;
  const int arow = wave*16 + lrow;
  const float* xrow = X + (size_t)aids[arow]*NDm + quad*8;

  // preload & convert all A fragments (GEMM1) up front
  short8 afs[12];
  #pragma unroll
  for (int kb=0; kb<12; kb++){
    const float* p = xrow + kb*32;
    #pragma unroll
    for (int j=0;j<8;j++) afs[kb][j] = f2bf(p[j]);
  }

  const float* W1s = W1 + s*NDm*NHm;
  float4v acc[12];
  #pragma unroll
  for (int i=0;i<12;i++){ acc[i][0]=0.f; acc[i][1]=0.f; acc[i][2]=0.f; acc[i][3]=0.f; }

  // ---- GEMM1: [64,384]@[384,192]
  for (int kb=0; kb<12; kb++){
    __syncthreads();
    for (int e = tid; e < 32*192; e += 256){
      int k = e / 192, c = e - k*192;
      Ws[c*40 + k] = f2bf(W1s[(kb*32 + k)*NHm + c]);
    }
    __syncthreads();
    short8 af = afs[kb];
    #pragma unroll
    for (int ct=0; ct<12; ct++){
      short8 bfb = *(const short8*)(&Ws[(ct*16 + lrow)*40 + quad*8]);
      acc[ct] = __builtin_amdgcn_mfma_f32_16x16x32_bf16(af, bfb, acc[ct], 0,0,0);
    }
  }
  // gelu -> Hs (bf16)
  #pragma unroll
  for (int ct=0; ct<12; ct++){
    #pragma unroll
    for (int r=0;r<4;r++){
      Hs[wave*16 + quad*4 + r][ct*16 + lrow] = f2bf(gelu_t(acc[ct][r]));
    }
  }

  // ---- GEMM2: [64,192]@[192,96]
  const float* W2s = W2 + s*NHm*NFm;
  float4v acc2[6];
  #pragma unroll
  for (int i=0;i<6;i++){ acc2[i][0]=0.f; acc2[i][1]=0.f; acc2[i][2]=0.f; acc2[i][3]=0.f; }
  for (int kb=0; kb<6; kb++){
    __syncthreads();
    for (int e = tid; e < 32*96; e += 256){
      int k = e / 96, c = e - k*96;
      Ws[c*40 + k] = f2bf(W2s[(kb*32 + k)*NFm + c]);
    }
    __syncthreads();
    short8 af2 = *(const short8*)(&Hs[wave*16 + lrow][kb*32 + quad*8]);
    #pragma unroll
    for (int ct=0; ct<6; ct++){
      short8 bfb = *(const short8*)(&Ws[(ct*16 + lrow)*40 + quad*8]);
      acc2[ct] = __builtin_amdgcn_mfma_f32_16x16x32_bf16(af2, bfb, acc2[ct], 0,0,0);
    }
  }
  // store internal (f32) + Is (bf16)
  #pragma unroll
  for (int ct=0; ct<6; ct++){
    #pragma unroll
    for (int r=0;r<4;r++){
      int row = wave*16 + quad*4 + r, col = ct*16 + lrow;
      float v = acc2[ct][r];
      if (row0 + row < cnt) internal_g[(size_t)aids[row]*NFm + col] = v;
      Is[row][col] = f2bf(v);
    }
  }

  // ---- GEMM3: [64,96]@[96,96]
  const float* Wns = Wn + s*NFm*NFm;
  float4v acc3[6];
  #pragma unroll
  for (int i=0;i<6;i++){ acc3[i][0]=0.f; acc3[i][1]=0.f; acc3[i][2]=0.f; acc3[i][3]=0.f; }
  for (int kb=0; kb<3; kb++){
    __syncthreads();
    for (int e = tid; e < 32*96; e += 256){
      int k = e / 96, c = e - k*96;
      Ws[c*40 + k] = f2bf(Wns[(kb*32 + k)*NFm + c]);
    }
    __syncthreads();
    short8 af3 = *(const short8*)(&Is[wave*16 + lrow][kb*32 + quad*8]);
    #pragma unroll
    for (int ct=0; ct<6; ct++){
      short8 bfb = *(const short8*)(&Ws[(ct*16 + lrow)*40 + quad*8]);
      acc3[ct] = __builtin_amdgcn_mfma_f32_16x16x32_bf16(af3, bfb, acc3[ct], 0,0,0);
    }
  }
  #pragma unroll
  for (int ct=0; ct<6; ct++){
    #pragma unroll
    for (int r=0;r<4;r++){
      int row = wave*16 + quad*4 + r, col = ct*16 + lrow;
      if (row0 + row < cnt) nbr_g[(size_t)aids[row]*NFm + col] = acc3[ct][r];
    }
  }
}

// ---------- per-atom head dots (Round-1 verified reduction pattern) ----------
// pre[i]      = dot(internal[i], Wf[sp[i]][0:96])
// nd4[i][s']  = dot(nbr[i],      Wf[s'][96:192])   for s'=0..3
// 192 threads = 2 atoms x 96 features.
__global__ void k_nd4(const float* __restrict__ internal, const float* __restrict__ nbr,
                      const int* __restrict__ sp, const float* __restrict__ Wf,
                      float* __restrict__ pre, float* __restrict__ nd4){
  __shared__ float red[2][5][128];
  int tid = threadIdx.x;
  int la = tid / 96, f = tid - la*96;
  int i = blockIdx.x*2 + la;
  int s = sp[i];
  float iv = internal[(size_t)i*NFm + f];
  float nv = nbr[(size_t)i*NFm + f];
  red[la][0][f] = iv * Wf[s*2*NFm + f];
  #pragma unroll
  for (int v=0; v<4; v++) red[la][1+v][f] = nv * Wf[v*2*NFm + NFm + f];
  if (f < 32){
    #pragma unroll
    for (int v=0; v<5; v++) red[la][v][96 + f] = 0.f;
  }
  __syncthreads();
  for (int off=64; off>0; off>>=1){
    if (f < off){
      #pragma unroll
      for (int v=0; v<5; v++) red[la][v][f] += red[la][v][f + off];
    }
    __syncthreads();
  }
  if (f == 0){
    pre[i] = red[la][0][0];
    #pragma unroll
    for (int v=0; v<4; v++) nd4[(size_t)i*4 + v] = red[la][1+v][0];
  }
}

// ---------- edge kernel: decay + 2 scalar atomicAdds per edge ----------
__global__ void k_edge2(const int* __restrict__ ai, const float* __restrict__ dist,
                        const float* __restrict__ pref, const float* __restrict__ fac,
                        const int* __restrict__ sp, const float* __restrict__ nd4,
                        float* __restrict__ pre){
  int e = blockIdx.x*256 + threadIdx.x;
  if (e >= NEe) return;
  int i0 = ai[e], i1 = ai[NEe + e];
  float d = dist[e];
  float x = (CUTOFF_ - d) * (1.0f/CUTOFF_);
  x = fminf(fmaxf(x, 0.f), 1.f);
  float sc = x*x*x*(x*(6.f*x - 15.f) + 10.f);
  float p = pref[0], fc = fac[0];
  float w = p*p * expf(-fc*fc*d) * sc;
  int s0 = sp[i0], s1 = sp[i1];
  atomicAdd(&pre[i0], w * nd4[(size_t)i1*4 + s0]);
  atomicAdd(&pre[i1], w * nd4[(size_t)i0*4 + s1]);
}

// ---------- per-molecule charge redistribution + species passthrough ----------
__global__ void k_finalize(const int* __restrict__ sp, const float* __restrict__ tc,
                           const float* __restrict__ pre, float* __restrict__ out){
  __shared__ float red[128];
  int b = blockIdx.x, t = threadIdx.x;
  float p = (t < NAm) ? pre[b*NAm + t] : 0.f;
  red[t] = p;
  __syncthreads();
  for (int off=64; off>0; off>>=1){
    if (t < off) red[t] += red[t + off];
    __syncthreads();
  }
  float sum = red[0];
  if (t < NAm){
    float c = p + (tc[b] - sum) * (1.0f/96.0f);
    out[b*NAm + t] = (float)sp[b*NAm + t];        // species as float
    out[NATOMS + b*NAm + t] = c;                  // charges
  }
}

extern "C" void kernel_launch(void* const* d_in, const int* in_sizes, int n_in,
                              void* d_out, int out_size, void* d_ws, size_t ws_size,
                              hipStream_t stream) {
  const int*   species = (const int*)  d_in[0];
  const float* X       = (const float*)d_in[1];
  const int*   ai      = (const int*)  d_in[2];
  const float* dist    = (const float*)d_in[3];
  const float* tc      = (const float*)d_in[4];
  const float* W1      = (const float*)d_in[5];
  const float* W2      = (const float*)d_in[6];
  const float* Wn      = (const float*)d_in[7];
  const float* Wf      = (const float*)d_in[8];
  const float* pref    = (const float*)d_in[9];
  const float* fac     = (const float*)d_in[10];
  float* out = (float*)d_out;
  float* pre = out + 2*NATOMS;    // precharges region of output, accumulated in place

  char* w = (char*)d_ws;
  auto alloc = [&](size_t bytes)->char*{
    char* p = w; w += (bytes + 255) & ~(size_t)255; return p;
  };
  int*   spc      = (int*)  alloc(64);
  int*   sps      = (int*)  alloc(64);
  int*   spcur    = (int*)  alloc(64);
  int*   order    = (int*)  alloc((size_t)NATOMS*4);
  float* nd4      = (float*)alloc((size_t)NATOMS*4*4);
  float* internal = (float*)alloc((size_t)NATOMS*NFm*4);
  float* nbr      = (float*)alloc((size_t)NATOMS*NFm*4);

  k_zero4<<<1, 64, 0, stream>>>(spc);
  k_spcount<<<NATOMS/256, 256, 0, stream>>>(species, spc);
  k_spscan<<<1, 64, 0, stream>>>(spc, sps, spcur);
  k_spscatter<<<NATOMS/256, 256, 0, stream>>>(species, spcur, order);
  dim3 g(NATOMS/64, NSm);
  k_mlp<<<g, 256, 0, stream>>>(X, order, sps, W1, W2, Wn, internal, nbr);
  k_nd4<<<NATOMS/2, 192, 0, stream>>>(internal, nbr, species, Wf, pre, nd4);
  k_edge2<<<(NEe+255)/256, 256, 0, stream>>>(ai, dist, pref, fac, species, nd4, pre);
  k_finalize<<<NBm, 128, 0, stream>>>(species, tc, pre, out);
}

// Round 4
// 238.535 us; speedup vs baseline: 2.4017x; 1.1645x over previous
//
#include <hip/hip_runtime.h>
#include <cstdint>
#include <cstddef>

#define NBm 256
#define NAm 96
#define NDm 384
#define NHm 192
#define NFm 96
#define NSm 4
#define NATOMS (NBm*NAm)      /* 24576 */
#define NEe (NATOMS*32)       /* 786432 */
#define CUTOFF_ 5.2f

typedef __attribute__((ext_vector_type(8))) short short8;
typedef __attribute__((ext_vector_type(4))) float float4v;

__device__ __forceinline__ short f2bf(float f){
  union { float f; unsigned u; } v; v.f = f;
  unsigned r = v.u + 0x7FFFu + ((v.u >> 16) & 1u);
  return (short)(r >> 16);
}

// jax.nn.gelu default: tanh approximation
__device__ __forceinline__ float gelu_t(float x){
  float u = 0.7978845608028654f * (x + 0.044715f * x*x*x);
  float e = __expf(-2.0f * fabsf(u));
  float t = (1.0f - e) / (1.0f + e);
  t = (u >= 0.f) ? t : -t;
  return 0.5f * x * (1.0f + t);
}

// ---------- species sort ----------
__global__ void k_zero4(int* __restrict__ spc){
  if (threadIdx.x < NSm) spc[threadIdx.x] = 0;
}

__global__ void k_spcount(const int* __restrict__ sp, int* __restrict__ spc){
  __shared__ int h[NSm];
  int t = threadIdx.x;
  if (t < NSm) h[t] = 0;
  __syncthreads();
  int i = blockIdx.x*256 + t;     // grid = 96 exact
  atomicAdd(&h[sp[i]], 1);
  __syncthreads();
  if (t < NSm) atomicAdd(&spc[t], h[t]);
}

__global__ void k_spscan(const int* __restrict__ spc, int* __restrict__ sps, int* __restrict__ spcur){
  if (threadIdx.x==0 && blockIdx.x==0){
    int r=0;
    for (int s=0;s<NSm;s++){ sps[s]=r; spcur[s]=r; r+=spc[s]; }
    sps[NSm]=r;
  }
}

__global__ void k_spscatter(const int* __restrict__ sp, int* __restrict__ spcur,
                            int* __restrict__ order){
  __shared__ int h[NSm], base[NSm];
  int t = threadIdx.x;
  if (t < NSm) h[t]=0;
  __syncthreads();
  int i = blockIdx.x*256 + t;
  int s = sp[i];
  int lr = atomicAdd(&h[s], 1);
  __syncthreads();
  if (t < NSm) base[t] = atomicAdd(&spcur[t], h[t]);
  __syncthreads();
  order[base[s] + lr] = i;
}

// ---------- weight prep: f32 -> bf16 transposed [s][col][k] ----------
#define W1N (NSm*NDm*NHm)   /* 294912 */
#define W2N (NSm*NHm*NFm)   /* 73728 */
#define WNN (NSm*NFm*NFm)   /* 36864 */
__global__ void k_wprep(const float* __restrict__ W1, const float* __restrict__ W2,
                        const float* __restrict__ Wn,
                        short* __restrict__ W1t, short* __restrict__ W2t,
                        short* __restrict__ Wnt){
  int idx = blockIdx.x*256 + threadIdx.x;
  if (idx < W1N){
    int s = idx / (NDm*NHm); int rem = idx - s*NDm*NHm;
    int k = rem / NHm, c = rem - k*NHm;
    W1t[(s*NHm + c)*NDm + k] = f2bf(W1[idx]);
  } else if (idx < W1N + W2N){
    int j = idx - W1N;
    int s = j / (NHm*NFm); int rem = j - s*NHm*NFm;
    int k = rem / NFm, c = rem - k*NFm;
    W2t[(s*NFm + c)*NHm + k] = f2bf(W2[j]);
  } else if (idx < W1N + W2N + WNN){
    int j = idx - W1N - W2N;
    int s = j / (NFm*NFm); int rem = j - s*NFm*NFm;
    int k = rem / NFm, c = rem - k*NFm;
    Wnt[(s*NFm + c)*NFm + k] = f2bf(Wn[j]);
  }
}

// ---------- X prep: f32 -> bf16 row-major, 8 elems/thread ----------
__global__ void k_xprep(const float* __restrict__ X, short* __restrict__ Xb){
  int i = (blockIdx.x*256 + threadIdx.x) * 8;   // grid exact: NATOMS*NDm/8/256 = 4608
  float4v a = *(const float4v*)(X + i);
  float4v b = *(const float4v*)(X + i + 4);
  short8 o;
  o[0]=f2bf(a[0]); o[1]=f2bf(a[1]); o[2]=f2bf(a[2]); o[3]=f2bf(a[3]);
  o[4]=f2bf(b[0]); o[5]=f2bf(b[1]); o[6]=f2bf(b[2]); o[7]=f2bf(b[3]);
  *(short8*)(Xb + i) = o;
}

// ---------- fused per-species MLP (Round-3 verified structure; staging now
// pure short8 copies of pre-converted bf16 — values bit-identical to R3) ----------
// internal = gelu(X@W1)@W2 ; nbr = internal@Wn
// 64 rows/block, 4 waves, mfma_f32_16x16x32_bf16
// A layout: A[m=lane&15][k=quad*8+j]; B transposed in LDS: B[n=lane&15][k=quad*8+j]
// C/D layout: col=lane&15, row=quad*4+reg
__global__ __launch_bounds__(256) void k_mlp(
    const short* __restrict__ Xb, const int* __restrict__ order,
    const int* __restrict__ sps,
    const short* __restrict__ W1t, const short* __restrict__ W2t,
    const short* __restrict__ Wnt,
    float* __restrict__ internal_g, float* __restrict__ nbr_g){
  const int s = blockIdx.y;
  const int s0 = sps[s];
  const int cnt = sps[s+1] - s0;
  const int row0 = blockIdx.x * 64;
  if (row0 >= cnt) return;

  __shared__ short Hs[64][200];     // H tile bf16, padded
  __shared__ short Ws[192*40];      // transposed weight chunk [col][k<=32], padded to 40
  __shared__ short Is[64][104];     // internal tile bf16, padded
  __shared__ int aids[64];

  const int tid = threadIdx.x;
  if (tid < 64){
    int r = row0 + tid;
    aids[tid] = order[s0 + ((r < cnt) ? r : 0)];
  }
  __syncthreads();

  const int wave = tid >> 6, lane = tid & 63;
  const int lrow = lane & 15, quad = lane >> 4;
  const int arow = wave*16 + lrow;
  const short* xrow = Xb + (size_t)aids[arow]*NDm + quad*8;

  // preload all A fragments (GEMM1) up front — direct bf16 vector loads
  short8 afs[12];
  #pragma unroll
  for (int kb=0; kb<12; kb++) afs[kb] = *(const short8*)(xrow + kb*32);

  const short* W1s = W1t + (size_t)s*NHm*NDm;
  float4v acc[12];
  #pragma unroll
  for (int i=0;i<12;i++){ acc[i][0]=0.f; acc[i][1]=0.f; acc[i][2]=0.f; acc[i][3]=0.f; }

  // ---- GEMM1: [64,384]@[384,192]
  for (int kb=0; kb<12; kb++){
    __syncthreads();
    for (int e = tid; e < 192*4; e += 256){     // 768 short8 chunks
      int c = e >> 2, kq = (e & 3) * 8;
      *(short8*)(&Ws[c*40 + kq]) = *(const short8*)(W1s + c*NDm + kb*32 + kq);
    }
    __syncthreads();
    short8 af = afs[kb];
    #pragma unroll
    for (int ct=0; ct<12; ct++){
      short8 bfb = *(const short8*)(&Ws[(ct*16 + lrow)*40 + quad*8]);
      acc[ct] = __builtin_amdgcn_mfma_f32_16x16x32_bf16(af, bfb, acc[ct], 0,0,0);
    }
  }
  // gelu -> Hs (bf16)
  #pragma unroll
  for (int ct=0; ct<12; ct++){
    #pragma unroll
    for (int r=0;r<4;r++){
      Hs[wave*16 + quad*4 + r][ct*16 + lrow] = f2bf(gelu_t(acc[ct][r]));
    }
  }

  // ---- GEMM2: [64,192]@[192,96]
  const short* W2s = W2t + (size_t)s*NFm*NHm;
  float4v acc2[6];
  #pragma unroll
  for (int i=0;i<6;i++){ acc2[i][0]=0.f; acc2[i][1]=0.f; acc2[i][2]=0.f; acc2[i][3]=0.f; }
  for (int kb=0; kb<6; kb++){
    __syncthreads();
    for (int e = tid; e < 96*4; e += 256){      // 384 short8 chunks
      int c = e >> 2, kq = (e & 3) * 8;
      *(short8*)(&Ws[c*40 + kq]) = *(const short8*)(W2s + c*NHm + kb*32 + kq);
    }
    __syncthreads();
    short8 af2 = *(const short8*)(&Hs[wave*16 + lrow][kb*32 + quad*8]);
    #pragma unroll
    for (int ct=0; ct<6; ct++){
      short8 bfb = *(const short8*)(&Ws[(ct*16 + lrow)*40 + quad*8]);
      acc2[ct] = __builtin_amdgcn_mfma_f32_16x16x32_bf16(af2, bfb, acc2[ct], 0,0,0);
    }
  }
  // store internal (f32) + Is (bf16)
  #pragma unroll
  for (int ct=0; ct<6; ct++){
    #pragma unroll
    for (int r=0;r<4;r++){
      int row = wave*16 + quad*4 + r, col = ct*16 + lrow;
      float v = acc2[ct][r];
      if (row0 + row < cnt) internal_g[(size_t)aids[row]*NFm + col] = v;
      Is[row][col] = f2bf(v);
    }
  }

  // ---- GEMM3: [64,96]@[96,96]
  const short* Wns = Wnt + (size_t)s*NFm*NFm;
  float4v acc3[6];
  #pragma unroll
  for (int i=0;i<6;i++){ acc3[i][0]=0.f; acc3[i][1]=0.f; acc3[i][2]=0.f; acc3[i][3]=0.f; }
  for (int kb=0; kb<3; kb++){
    __syncthreads();
    for (int e = tid; e < 96*4; e += 256){
      int c = e >> 2, kq = (e & 3) * 8;
      *(short8*)(&Ws[c*40 + kq]) = *(const short8*)(Wns + c*NFm + kb*32 + kq);
    }
    __syncthreads();
    short8 af3 = *(const short8*)(&Is[wave*16 + lrow][kb*32 + quad*8]);
    #pragma unroll
    for (int ct=0; ct<6; ct++){
      short8 bfb = *(const short8*)(&Ws[(ct*16 + lrow)*40 + quad*8]);
      acc3[ct] = __builtin_amdgcn_mfma_f32_16x16x32_bf16(af3, bfb, acc3[ct], 0,0,0);
    }
  }
  #pragma unroll
  for (int ct=0; ct<6; ct++){
    #pragma unroll
    for (int r=0;r<4;r++){
      int row = wave*16 + quad*4 + r, col = ct*16 + lrow;
      if (row0 + row < cnt) nbr_g[(size_t)aids[row]*NFm + col] = acc3[ct][r];
    }
  }
}

// ---------- per-atom head dots: one wave per atom, xor-shuffle reduce ----------
// pre[i]      = dot(internal[i], Wf[sp[i]][0:96])
// nd4[i][s']  = dot(nbr[i],      Wf[s'][96:192])   for s'=0..3
__global__ void k_nd4(const float* __restrict__ internal, const float* __restrict__ nbr,
                      const int* __restrict__ sp, const float* __restrict__ Wf,
                      float* __restrict__ pre, float* __restrict__ nd4){
  int a = blockIdx.x*4 + (threadIdx.x >> 6);   // grid = NATOMS/4 exact
  int lane = threadIdx.x & 63;
  bool lo = lane < 32;
  const float* ip = internal + (size_t)a*NFm;
  const float* np = nbr + (size_t)a*NFm;
  float iv1 = ip[lane],            nv1 = np[lane];
  float iv2 = lo ? ip[64+lane]:0.f, nv2 = lo ? np[64+lane]:0.f;
  int s = sp[a];
  const float* wfs = Wf + s*2*NFm;
  float d = iv1*wfs[lane] + (lo ? iv2*wfs[64+lane] : 0.f);
  float n0, n1, n2, n3;
  {
    const float* w0 = Wf + 0*2*NFm + NFm;
    const float* w1 = Wf + 1*2*NFm + NFm;
    const float* w2 = Wf + 2*2*NFm + NFm;
    const float* w3 = Wf + 3*2*NFm + NFm;
    n0 = nv1*w0[lane] + (lo ? nv2*w0[64+lane] : 0.f);
    n1 = nv1*w1[lane] + (lo ? nv2*w1[64+lane] : 0.f);
    n2 = nv1*w2[lane] + (lo ? nv2*w2[64+lane] : 0.f);
    n3 = nv1*w3[lane] + (lo ? nv2*w3[64+lane] : 0.f);
  }
  #pragma unroll
  for (int m=1; m<64; m<<=1){
    d  += __shfl_xor(d,  m, 64);
    n0 += __shfl_xor(n0, m, 64);
    n1 += __shfl_xor(n1, m, 64);
    n2 += __shfl_xor(n2, m, 64);
    n3 += __shfl_xor(n3, m, 64);
  }
  if (lane == 0){
    pre[a] = d;
    float4v v; v[0]=n0; v[1]=n1; v[2]=n2; v[3]=n3;
    *(float4v*)(nd4 + (size_t)a*4) = v;
  }
}

// ---------- edge kernel: decay + 2 scalar atomicAdds per edge ----------
__global__ void k_edge2(const int* __restrict__ ai, const float* __restrict__ dist,
                        const float* __restrict__ pref, const float* __restrict__ fac,
                        const int* __restrict__ sp, const float* __restrict__ nd4,
                        float* __restrict__ pre){
  int e = blockIdx.x*256 + threadIdx.x;
  if (e >= NEe) return;
  int i0 = ai[e], i1 = ai[NEe + e];
  float d = dist[e];
  float x = (CUTOFF_ - d) * (1.0f/CUTOFF_);
  x = fminf(fmaxf(x, 0.f), 1.f);
  float sc = x*x*x*(x*(6.f*x - 15.f) + 10.f);
  float p = pref[0], fc = fac[0];
  float w = p*p * expf(-fc*fc*d) * sc;
  int s0 = sp[i0], s1 = sp[i1];
  float4v v1 = *(const float4v*)(nd4 + (size_t)i1*4);
  float4v v0 = *(const float4v*)(nd4 + (size_t)i0*4);
  float g0 = (s0 < 2) ? ((s0 == 0) ? v1[0] : v1[1]) : ((s0 == 2) ? v1[2] : v1[3]);
  float g1 = (s1 < 2) ? ((s1 == 0) ? v0[0] : v0[1]) : ((s1 == 2) ? v0[2] : v0[3]);
  atomicAdd(&pre[i0], w * g0);
  atomicAdd(&pre[i1], w * g1);
}

// ---------- per-molecule charge redistribution + species passthrough ----------
__global__ void k_finalize(const int* __restrict__ sp, const float* __restrict__ tc,
                           const float* __restrict__ pre, float* __restrict__ out){
  __shared__ float red[128];
  int b = blockIdx.x, t = threadIdx.x;
  float p = (t < NAm) ? pre[b*NAm + t] : 0.f;
  red[t] = p;
  __syncthreads();
  for (int off=64; off>0; off>>=1){
    if (t < off) red[t] += red[t + off];
    __syncthreads();
  }
  float sum = red[0];
  if (t < NAm){
    float c = p + (tc[b] - sum) * (1.0f/96.0f);
    out[b*NAm + t] = (float)sp[b*NAm + t];        // species as float
    out[NATOMS + b*NAm + t] = c;                  // charges
  }
}

extern "C" void kernel_launch(void* const* d_in, const int* in_sizes, int n_in,
                              void* d_out, int out_size, void* d_ws, size_t ws_size,
                              hipStream_t stream) {
  const int*   species = (const int*)  d_in[0];
  const float* X       = (const float*)d_in[1];
  const int*   ai      = (const int*)  d_in[2];
  const float* dist    = (const float*)d_in[3];
  const float* tc      = (const float*)d_in[4];
  const float* W1      = (const float*)d_in[5];
  const float* W2      = (const float*)d_in[6];
  const float* Wn      = (const float*)d_in[7];
  const float* Wf      = (const float*)d_in[8];
  const float* pref    = (const float*)d_in[9];
  const float* fac     = (const float*)d_in[10];
  float* out = (float*)d_out;
  float* pre = out + 2*NATOMS;    // precharges region of output, accumulated in place

  char* w = (char*)d_ws;
  auto alloc = [&](size_t bytes)->char*{
    char* p = w; w += (bytes + 255) & ~(size_t)255; return p;
  };
  int*   spc      = (int*)  alloc(64);
  int*   sps      = (int*)  alloc(64);
  int*   spcur    = (int*)  alloc(64);
  int*   order    = (int*)  alloc((size_t)NATOMS*4);
  float* nd4      = (float*)alloc((size_t)NATOMS*4*4);
  float* internal = (float*)alloc((size_t)NATOMS*NFm*4);
  float* nbr      = (float*)alloc((size_t)NATOMS*NFm*4);
  short* W1t      = (short*)alloc((size_t)W1N*2);
  short* W2t      = (short*)alloc((size_t)W2N*2);
  short* Wnt      = (short*)alloc((size_t)WNN*2);
  short* Xb       = (short*)alloc((size_t)NATOMS*NDm*2);

  k_zero4<<<1, 64, 0, stream>>>(spc);
  k_wprep<<<(W1N+W2N+WNN)/256, 256, 0, stream>>>(W1, W2, Wn, W1t, W2t, Wnt);
  k_xprep<<<NATOMS*NDm/8/256, 256, 0, stream>>>(X, Xb);
  k_spcount<<<NATOMS/256, 256, 0, stream>>>(species, spc);
  k_spscan<<<1, 64, 0, stream>>>(spc, sps, spcur);
  k_spscatter<<<NATOMS/256, 256, 0, stream>>>(species, spcur, order);
  dim3 g(NATOMS/64, NSm);
  k_mlp<<<g, 256, 0, stream>>>(Xb, order, sps, W1t, W2t, Wnt, internal, nbr);
  k_nd4<<<NATOMS/4, 256, 0, stream>>>(internal, nbr, species, Wf, pre, nd4);
  k_edge2<<<(NEe+255)/256, 256, 0, stream>>>(ai, dist, pref, fac, species, nd4, pre);
  k_finalize<<<NBm, 128, 0, stream>>>(species, tc, pre, out);
}